// Round 5
// baseline (487.918 us; speedup 1.0000x reference)
//
#include <hip/hip_runtime.h>

// BiLSTM (diagonal, PixelRNN-style) on MI355X.
// R4: k=4 scan steps per launch via halo recompute (8 launches instead of 32).
// Block owns 2 rows, stages 6 rows (own + halo cone) of lh into LDS
// (double-buffered, 48KB, XOR-swizzled); one __syncthreads per step.
// lc lives in registers (fixed (px,c)->thread map); acc streamed per tile;
// hmap2 [p][c][4gates] read from global (XCD-local strip placement).

using bf16   = __bf16;
using bf16x8 = __attribute__((ext_vector_type(8))) __bf16;
using f32x4  = __attribute__((ext_vector_type(4))) float;

__device__ __forceinline__ float sigf(float x) {
  return __builtin_amdgcn_rcpf(1.0f + __expf(-x));
}
__device__ __forceinline__ float tanh_fast(float x) {
  return 2.0f * __builtin_amdgcn_rcpf(1.0f + __expf(-2.0f * x)) - 1.0f;
}
__device__ __forceinline__ bf16x8 bzero8() {
  bf16x8 v;
#pragma unroll
  for (int e = 0; e < 8; ++e) v[e] = (bf16)0.0f;
  return v;
}
__device__ __forceinline__ unsigned short f2bu(float f) {
  bf16 b = (bf16)f;
  return __builtin_bit_cast(unsigned short, b);
}
__device__ __forceinline__ float bu2f(unsigned short u) {
  return __uint_as_float(((unsigned)u) << 16);
}

// ---------------- prep: weights -> bf16, [n][k] layouts ----------------
__global__ void prep_kernel(const float* __restrict__ w_i2s,
                            const float* __restrict__ w_left,
                            const float* __restrict__ w_right,
                            const float* __restrict__ w_skip,
                            bf16* __restrict__ WnI, bf16* __restrict__ WnL,
                            bf16* __restrict__ WnR, bf16* __restrict__ WnS) {
  int t = blockIdx.x * 256 + threadIdx.x;
  if (t < 32768) {
    WnI[t] = (bf16)w_i2s[t];  // [256][128] o-major == desired [n][k]
    int o = t >> 7, k = t & 127;
    // k<64: tap0 (h-1, w+-1) -> w[:,:,0]; k>=64: tap1 (h, w+-1) -> w[:,:,1]
    int src = (k < 64) ? (o * 128 + k * 2) : (o * 128 + (k - 64) * 2 + 1);
    WnL[t] = (bf16)w_left[src];
    WnR[t] = (bf16)w_right[src];
    if (t < 8192) WnS[t] = (bf16)w_skip[t];  // [128][64]
  }
}

// ------- hmap2 = pack(x @ w_i2s^T) : [p][c][4 gates] ushort4 (bf16 bits) -------
__global__ __launch_bounds__(256, 2)
void hmap_kernel(const float* __restrict__ x, const bf16* __restrict__ Wn,
                 ushort* __restrict__ hmap2) {
  __shared__ __align__(16) bf16 At[64 * 128];  // XOR-swizzled
  const int tile = blockIdx.x;  // 256 tiles: 64 px each (2 rows of one batch)
  const int b = tile >> 4, h0 = (tile & 15) << 1;
  const int t = threadIdx.x;
  const float* xb = x + (size_t)(b * 128) * 1024 + h0 * 32;
#pragma unroll
  for (int i = 0; i < 8; ++i) {
    int idx = t + 256 * i;          // [0,2048)
    int c = idx >> 4, m4 = idx & 15;
    f32x4 v = *(const f32x4*)(xb + (size_t)c * 1024 + m4 * 4);
#pragma unroll
    for (int e = 0; e < 4; ++e) {
      int m = m4 * 4 + e;
      int kb = (c * 2) ^ ((m & 7) << 4);
      *(bf16*)((char*)At + m * 256 + kb) = (bf16)v[e];
    }
  }
  __syncthreads();
  const int wv = t >> 6, l = t & 63;
  const int l15 = l & 15, lq = l >> 4;
  const int c = wv * 16 + l15;
  bf16x8 bfrag[4][4];
#pragma unroll
  for (int q = 0; q < 4; ++q)
#pragma unroll
    for (int kk = 0; kk < 4; ++kk)
      bfrag[q][kk] = *(const bf16x8*)(Wn + (q * 64 + c) * 128 + kk * 32 + lq * 8);
  f32x4 acc[4][4];
  const f32x4 fz = {0.f, 0.f, 0.f, 0.f};
#pragma unroll
  for (int ms = 0; ms < 4; ++ms)
#pragma unroll
    for (int q = 0; q < 4; ++q) acc[ms][q] = fz;
#pragma unroll
  for (int kk = 0; kk < 4; ++kk) {
#pragma unroll
    for (int ms = 0; ms < 4; ++ms) {
      int m = ms * 16 + l15;
      int kb = ((kk * 32 + lq * 8) * 2) ^ ((m & 7) << 4);
      bf16x8 a = *(const bf16x8*)((const char*)At + m * 256 + kb);
#pragma unroll
      for (int q = 0; q < 4; ++q)
        acc[ms][q] =
            __builtin_amdgcn_mfma_f32_16x16x32_bf16(a, bfrag[q][kk], acc[ms][q], 0, 0, 0);
    }
  }
  const int pix0 = tile * 64;
#pragma unroll
  for (int ms = 0; ms < 4; ++ms)
#pragma unroll
    for (int j = 0; j < 4; ++j) {
      int p = pix0 + ms * 16 + lq * 4 + j;
      ushort4 hv;
      hv.x = f2bu(acc[ms][0][j]);
      hv.y = f2bu(acc[ms][1][j]);
      hv.z = f2bu(acc[ms][2][j]);
      hv.w = f2bu(acc[ms][3][j]);
      ((ushort4*)hmap2)[(size_t)p * 64 + c] = hv;
    }
}

// ---------------- four scan steps per launch (halo recompute) ----------------
// 512 blocks; strip placement keyed to blk%8 so both strips sharing halo rows
// land on one XCD (perf heuristic only). Block owns global rows {r0, r0+1},
// stages local rows 0..5 (= global r0-4 .. r0+1) of lh into LDS.
// Local row r at step s is valid iff r >= s and its global row >= 0.
__global__ __launch_bounds__(256, 2)
void step4_kernel(const bf16* __restrict__ lhLin, bf16* __restrict__ lhLout,
                  const bf16* __restrict__ lhRin, bf16* __restrict__ lhRout,
                  const float* __restrict__ lcLin, float* __restrict__ lcLout,
                  const float* __restrict__ lcRin, float* __restrict__ lcRout,
                  const ushort* __restrict__ hmap2,
                  const bf16* __restrict__ WnL, const bf16* __restrict__ WnR,
                  const float* __restrict__ bL, const float* __restrict__ bR) {
  __shared__ __align__(16) bf16 lhs[2][6 * 32 * 64];  // 2 x 24 KB, swizzled
  const int blk = blockIdx.x;
  const int x8 = blk & 7, y = blk >> 3;   // y in [0,64)
  const int strip = 2 * x8 + (y & 1);     // [0,16)
  const int bs = y >> 1;                  // [0,32) = batch*2 + stream
  const bool right = (bs & 1) != 0;
  const int b = bs >> 1;
  const int r0 = strip * 2;
  const int t = threadIdx.x;
  const int dw = right ? 1 : -1;
  const bf16* __restrict__ lin = right ? lhRin : lhLin;
  bf16* __restrict__ lout = right ? lhRout : lhLout;
  const float* __restrict__ lcIn = right ? lcRin : lcLin;
  float* __restrict__ lcOut = right ? lcRout : lcLout;
  const bf16* __restrict__ Wn = right ? WnR : WnL;
  const float* __restrict__ bias = right ? bR : bL;

  const int wv = t >> 6, l = t & 63, l15 = l & 15, lq = l >> 4;
  const int c = wv * 16 + l15;  // channel this lane owns (gate-interleaved N)

  // ---- stage lh rows r0-4..r0+1 into BOTH LDS buffers (g<0 -> zeros) ----
#pragma unroll
  for (int i = 0; i < 6; ++i) {
    int idx = t + 256 * i;        // [0,1536)
    int pxl = idx >> 3, c8 = idx & 7;
    int row = pxl >> 5, w = pxl & 31;
    int g = r0 - 4 + row;
    bf16x8 v = bzero8();
    if (g >= 0)
      v = *(const bf16x8*)(lin + (size_t)((b * 32 + g) * 32 + w) * 64 + c8 * 8);
    int off = (pxl * 128 + c8 * 16) ^ ((pxl & 7) << 4);
    *(bf16x8*)((char*)lhs[0] + off) = v;
    *(bf16x8*)((char*)lhs[1] + off) = v;
  }

  // ---- loop-invariant registers ----
  bf16x8 bfrag[4][4];
#pragma unroll
  for (int q = 0; q < 4; ++q)
#pragma unroll
    for (int kk = 0; kk < 4; ++kk)
      bfrag[q][kk] = *(const bf16x8*)(Wn + (q * 64 + c) * 128 + kk * 32 + lq * 8);
  float bq[4];
#pragma unroll
  for (int q = 0; q < 4; ++q) bq[q] = bias[q * 64 + c];

  // lc registers for local rows 1..5 (tiles mt 2..11)
  float lc_r[10][4];
#pragma unroll
  for (int mt = 2; mt < 12; ++mt) {
    int row = mt >> 1, g = r0 - 4 + row;
#pragma unroll
    for (int j = 0; j < 4; ++j) {
      int we = (mt & 1) * 16 + lq * 4 + j;
      float v = 0.0f;
      if (g >= 0) v = lcIn[(size_t)(b * 1024 + g * 32 + we) * 64 + c];
      lc_r[mt - 2][j] = v;
    }
  }
  const int mtmin_g = (strip == 0) ? 8 : (strip == 1 ? 4 : 0);
  __syncthreads();

  // ---- 4 steps; read lhs[(s+1)&1], write lhs[s&1]; one barrier per step ----
  for (int s = 1; s <= 4; ++s) {
    const char* rb = (const char*)lhs[(s + 1) & 1];
    char* wb = (char*)lhs[s & 1];
    const int mtmin = (2 * s > mtmin_g) ? 2 * s : mtmin_g;
#pragma unroll
    for (int mt = 2; mt < 12; ++mt) {
      if (mt >= mtmin) {
        const int row = mt >> 1, wbase = (mt & 1) * 16;
        // GEMM: A-frags from LDS (old buffer)
        const int wsrc = wbase + l15 + dw;
        const bool oob = (unsigned)wsrc >= 32u;
        const int wc = wsrc & 31;
        f32x4 acc[4];
        const f32x4 fz = {0.f, 0.f, 0.f, 0.f};
#pragma unroll
        for (int q = 0; q < 4; ++q) acc[q] = fz;
#pragma unroll
        for (int kk = 0; kk < 4; ++kk) {
          const int tap = kk >> 1;
          const int c0 = (kk & 1) * 32 + lq * 8;
          const int rs = row - 1 + tap;
          int off = (((rs * 32 + wc) * 128) + c0 * 2) ^ ((wc & 7) << 4);
          bf16x8 a = *(const bf16x8*)(rb + off);
          if (oob) a = bzero8();
#pragma unroll
          for (int q = 0; q < 4; ++q)
            acc[q] = __builtin_amdgcn_mfma_f32_16x16x32_bf16(a, bfrag[q][kk], acc[q], 0, 0, 0);
        }
        // epilogue: gates, lc (regs), lh -> LDS (new buffer)
        const int g = r0 - 4 + row;
#pragma unroll
        for (int j = 0; j < 4; ++j) {
          const int we = wbase + lq * 4 + j;
          const size_t p = (size_t)(b * 1024 + g * 32 + we);
          ushort4 hm = ((const ushort4*)hmap2)[p * 64 + c];
          float pre0 = acc[0][j] + bu2f(hm.x) + bq[0];
          float pre1 = acc[1][j] + bu2f(hm.y) + bq[1];
          float pre2 = acc[2][j] + bu2f(hm.z) + bq[2];
          float pre3 = acc[3][j] + bu2f(hm.w) + bq[3];
          float og = sigf(pre0), fg = sigf(pre1), ig = sigf(pre2), gg = sigf(pre3);
          float lcv = fg * lc_r[mt - 2][j] + ig * gg;
          lc_r[mt - 2][j] = lcv;
          int woff = (((row * 32 + we) * 128) + c * 2) ^ ((we & 7) << 4);
          *(bf16*)(wb + woff) = (bf16)(og * tanh_fast(lcv));
        }
      }
    }
    __syncthreads();
  }

  // ---- writeback owned rows (local 4,5) : lh from lhs[0], lc from regs ----
#pragma unroll
  for (int i = 0; i < 2; ++i) {
    int idx = t + 256 * i;  // [0,512)
    int px2 = idx >> 3, c8 = idx & 7;
    int rloc = px2 >> 5, w = px2 & 31;
    int off = ((128 + px2) * 128 + c8 * 16) ^ ((px2 & 7) << 4);
    bf16x8 v = *(const bf16x8*)((const char*)lhs[0] + off);
    *(bf16x8*)(lout + (size_t)((b * 32 + r0 + rloc) * 32 + w) * 64 + c8 * 8) = v;
  }
#pragma unroll
  for (int mt = 8; mt < 12; ++mt) {
    int row = mt >> 1, g = r0 - 4 + row;
#pragma unroll
    for (int j = 0; j < 4; ++j) {
      int we = (mt & 1) * 16 + lq * 4 + j;
      lcOut[(size_t)(b * 1024 + g * 32 + we) * 64 + c] = lc_r[mt - 2][j];
    }
  }
}

// ---------------- final: out = x + (lhL + shift_down(lhR)) @ w_skip^T + b ----------------
__global__ __launch_bounds__(256, 2)
void final_kernel(const float* __restrict__ x, const bf16* __restrict__ lhL,
                  const bf16* __restrict__ lhR, const bf16* __restrict__ Wn,
                  const float* __restrict__ b_skip, float* __restrict__ out) {
  __shared__ __align__(16) bf16 At[64 * 64];
  __shared__ __align__(16) float smemT[128 * 72];  // [o2][m], padded rows
  const int tile = blockIdx.x;
  const int b = tile >> 4, h0 = (tile & 15) << 1;
  const int t = threadIdx.x;
#pragma unroll
  for (int i = 0; i < 2; ++i) {
    int idx = t + 256 * i;  // [0,512)
    int m = idx >> 3, c8 = idx & 7;
    int h = h0 + (m >> 5), w = m & 31;
    size_t p = (size_t)(b * 32 + h) * 32 + w;
    bf16x8 vL = *(const bf16x8*)(lhL + p * 64 + c8 * 8);
    bf16x8 v;
    if (h > 0) {
      bf16x8 vR = *(const bf16x8*)(lhR + (p - 32) * 64 + c8 * 8);
#pragma unroll
      for (int e = 0; e < 8; ++e) v[e] = (bf16)((float)vL[e] + (float)vR[e]);
    } else {
      v = vL;
    }
    int kb = (c8 * 16) ^ ((m & 7) << 4);
    *(bf16x8*)((char*)At + m * 128 + kb) = v;
  }
  __syncthreads();
  const int wv = t >> 6, l = t & 63;
  const int l15 = l & 15, lq = l >> 4;
  const int c = wv * 16 + l15;
  bf16x8 bfrag[2][2];
#pragma unroll
  for (int q = 0; q < 2; ++q)
#pragma unroll
    for (int kk = 0; kk < 2; ++kk)
      bfrag[q][kk] = *(const bf16x8*)(Wn + (q * 64 + c) * 64 + kk * 32 + lq * 8);
  f32x4 acc[4][2];
  const f32x4 fz = {0.f, 0.f, 0.f, 0.f};
#pragma unroll
  for (int ms = 0; ms < 4; ++ms)
#pragma unroll
    for (int q = 0; q < 2; ++q) acc[ms][q] = fz;
#pragma unroll
  for (int kk = 0; kk < 2; ++kk) {
#pragma unroll
    for (int ms = 0; ms < 4; ++ms) {
      int m = ms * 16 + l15;
      int kb = ((kk * 32 + lq * 8) * 2) ^ ((m & 7) << 4);
      bf16x8 a = *(const bf16x8*)((const char*)At + m * 128 + kb);
#pragma unroll
      for (int q = 0; q < 2; ++q)
        acc[ms][q] =
            __builtin_amdgcn_mfma_f32_16x16x32_bf16(a, bfrag[q][kk], acc[ms][q], 0, 0, 0);
    }
  }
  float bsk[2];
#pragma unroll
  for (int q = 0; q < 2; ++q) bsk[q] = b_skip[q * 64 + c];
#pragma unroll
  for (int ms = 0; ms < 4; ++ms)
#pragma unroll
    for (int q = 0; q < 2; ++q)
#pragma unroll
      for (int j = 0; j < 4; ++j) {
        int m = ms * 16 + lq * 4 + j;
        int n = q * 64 + c;
        smemT[n * 72 + m] = acc[ms][q][j] + bsk[q];
      }
  __syncthreads();
  const float* xb = x + (size_t)(b * 128) * 1024 + h0 * 32;
  float* ob = out + (size_t)(b * 128) * 1024 + h0 * 32;
#pragma unroll
  for (int i = 0; i < 8; ++i) {
    int idx = t + 256 * i;  // [0,2048)
    int o2 = idx >> 4, m4 = idx & 15;
    f32x4 s = *(const f32x4*)(&smemT[o2 * 72 + m4 * 4]);
    f32x4 xv = *(const f32x4*)(xb + (size_t)o2 * 1024 + m4 * 4);
#pragma unroll
    for (int e = 0; e < 4; ++e) s[e] += xv[e];
    *(f32x4*)(ob + (size_t)o2 * 1024 + m4 * 4) = s;
  }
}

extern "C" void kernel_launch(void* const* d_in, const int* in_sizes, int n_in,
                              void* d_out, int out_size, void* d_ws, size_t ws_size,
                              hipStream_t stream) {
  const float* x       = (const float*)d_in[0];
  const float* w_i2s   = (const float*)d_in[1];
  const float* w_left  = (const float*)d_in[2];
  const float* b_left  = (const float*)d_in[3];
  const float* w_right = (const float*)d_in[4];
  const float* b_right = (const float*)d_in[5];
  const float* w_skip  = (const float*)d_in[6];
  const float* b_skip  = (const float*)d_in[7];
  float* out = (float*)d_out;
  char* ws = (char*)d_ws;

  // ws layout (bytes); total ~32.3 MB
  bf16*   lhL0  = (bf16*)(ws + 0x0000000);   // 2 MB (zeroed)
  bf16*   lhR0  = (bf16*)(ws + 0x0200000);   // 2 MB (zeroed)
  float*  lcL0  = (float*)(ws + 0x0400000);  // 4 MB (zeroed)
  float*  lcR0  = (float*)(ws + 0x0800000);  // 4 MB (zeroed)
  bf16*   lhL1  = (bf16*)(ws + 0x0C00000);   // 2 MB
  bf16*   lhR1  = (bf16*)(ws + 0x0E00000);   // 2 MB
  float*  lcL1  = (float*)(ws + 0x1000000);  // 4 MB
  float*  lcR1  = (float*)(ws + 0x1400000);  // 4 MB
  ushort* hmap2 = (ushort*)(ws + 0x1800000); // 8 MB
  bf16*   WnI   = (bf16*)(ws + 0x2000000);   // 64 KB
  bf16*   WnL   = (bf16*)(ws + 0x2010000);
  bf16*   WnR   = (bf16*)(ws + 0x2020000);
  bf16*   WnS   = (bf16*)(ws + 0x2030000);

  // zero initial lh + lc (contiguous 12 MB)
  hipMemsetAsync(ws, 0, 0x0C00000, stream);
  prep_kernel<<<128, 256, 0, stream>>>(w_i2s, w_left, w_right, w_skip, WnI, WnL, WnR, WnS);
  hmap_kernel<<<256, 256, 0, stream>>>(x, WnI, hmap2);
  for (int i = 0; i < 8; ++i) {
    bf16*  liL = (i & 1) ? lhL1 : lhL0;
    bf16*  loL = (i & 1) ? lhL0 : lhL1;
    bf16*  liR = (i & 1) ? lhR1 : lhR0;
    bf16*  loR = (i & 1) ? lhR0 : lhR1;
    float* ciL = (i & 1) ? lcL1 : lcL0;
    float* coL = (i & 1) ? lcL0 : lcL1;
    float* ciR = (i & 1) ? lcR1 : lcR0;
    float* coR = (i & 1) ? lcR0 : lcR1;
    step4_kernel<<<512, 256, 0, stream>>>(liL, loL, liR, loR, ciL, coL, ciR, coR,
                                          hmap2, WnL, WnR, b_left, b_right);
  }
  // after 8 launches x 4 steps = 32 steps, final state is in buffer 0
  final_kernel<<<256, 256, 0, stream>>>(x, lhL0, lhR0, WnS, b_skip, out);
}